// Round 1
// baseline (355.898 us; speedup 1.0000x reference)
//
#include <hip/hip_runtime.h>

typedef __attribute__((ext_vector_type(8))) short bf16x8_t;
typedef __attribute__((ext_vector_type(4))) float f32x4_t;

#define BATCH 4
#define CH 64
#define HIN 256
#define WIN 512
#define NDISP 65
#define TY 4
#define TX 254
#define NP0 128   // parity positions for x0 tile (x' span 256)
#define NP1 192   // parity positions for x1 tile (v span 384)

// LDS byte offsets
#define X0_OFF 0
#define X0_PS (NP0*64)            // 8192 per parity
#define X1_OFF 16384
#define X1_PS (NP1*64)            // 12288 per parity
#define S0A_OFF 40960             // float[4][256]
#define SQ0A_OFF 45056            // float[4][256]
#define S1A_OFF 49152             // float[4][384]
#define SQ1A_OFF 55296            // float[4][384]
#define QB_OFF 61440              // float[65][257] = 66820B
#define S0X_OFF 128272            // float[254] (pad to 256)
#define L0X_OFF 129296
#define S1X_OFF 130320            // float[382] (pad to 384)
#define L1X_OFF 131856
#define SMEM_BYTES 133392

__device__ __forceinline__ unsigned short f2bf(float f) {
  unsigned u = __float_as_uint(f);
  u += 0x7fffu + ((u >> 16) & 1u);          // RNE
  return (unsigned short)(u >> 16);
}
__device__ __forceinline__ float bf2f(unsigned short h) {
  return __uint_as_float(((unsigned)h) << 16);
}

__global__ __launch_bounds__(512, 2)
void corrzn_kernel(const float* __restrict__ x0, const float* __restrict__ x1,
                   float* __restrict__ out) {
  __shared__ __align__(16) char smem[SMEM_BYTES];

  const int tid  = threadIdx.x;
  const int lane = tid & 63;
  const int wv   = tid >> 6;      // 0..7
  const int p    = wv & 1;        // parity this wave works on
  const int jj   = wv >> 1;       // 0..3
  const int chunk0 = 2 * jj;      // wave's M-chunks: chunk0, chunk0+1 (of 8 per parity)
  const int lm = lane & 15;
  const int lk = lane >> 4;

  const int x0blk = blockIdx.x * TX;       // 0, 254, 508
  const int y0    = blockIdx.y * TY;       // output row base
  const int b     = blockIdx.z;

  const size_t plane = (size_t)HIN * WIN;
  const float* x0b = x0 + (size_t)b * CH * plane;
  const float* x1b = x1 + (size_t)b * CH * plane;

  float* s0a  = (float*)(smem + S0A_OFF);
  float* sq0a = (float*)(smem + SQ0A_OFF);
  float* s1a  = (float*)(smem + S1A_OFF);
  float* sq1a = (float*)(smem + SQ1A_OFF);

  // zero the stats region (contiguous 20480B = 5120 floats)
  for (int i = tid; i < 5120; i += 512) s0a[i] = 0.f;

  f32x4_t acc[TY][2][5];
#pragma unroll
  for (int t = 0; t < TY; ++t)
#pragma unroll
    for (int mc = 0; mc < 2; ++mc)
#pragma unroll
      for (int T = 0; T < 5; ++T)
        acc[t][mc][T] = (f32x4_t){0.f, 0.f, 0.f, 0.f};

  __syncthreads();

  // ================= K-loop: 6 padded rows x 2 channel chunks =================
  for (int r = 0; r < 6; ++r) {
    const int orow = y0 + r - 1;                       // original row (pad=1)
    const bool rowok = (orow >= 0) && (orow < HIN);
    for (int cc = 0; cc < 2; ++cc) {
      __syncthreads();
      // ---- stage row r, channels cc*32..+31 as bf16, parity-split, swizzled ----
#pragma unroll
      for (int it = 0; it < 10; ++it) {
        const int s = it * 512 + tid;                  // 0..5119
        const bool isx1 = (it >= 4);                   // iters 0-3: x0 (2048 slots), 4-9: x1 (3072)
        int cp, wp;
        if (!isx1) { cp = s >> 7; wp = s & 127; }
        else { const int s2 = s - 2048; cp = s2 / 192; wp = s2 - cp * 192; }
        const int cl = 2 * cp;                         // local channel (even)
        const int cg = cc * 32 + cl;                   // global channel
        const int w0 = isx1 ? (x0blk - 65 + 2 * wp) : (x0blk - 1 + 2 * wp);
        float v00 = 0.f, v01 = 0.f, v10 = 0.f, v11 = 0.f;
        if (rowok) {
          const float* src = (isx1 ? x1b : x0b) + (size_t)cg * plane + (size_t)orow * WIN;
          if (w0 >= 0 && w0 < WIN)         { v00 = src[w0];     v10 = src[plane + w0]; }
          if (w0 + 1 >= 0 && w0 + 1 < WIN) { v01 = src[w0 + 1]; v11 = src[plane + w0 + 1]; }
        }
        const unsigned pk0 = (unsigned)f2bf(v00) | ((unsigned)f2bf(v10) << 16); // (c, c+1) @ even local
        const unsigned pk1 = (unsigned)f2bf(v01) | ((unsigned)f2bf(v11) << 16); // (c, c+1) @ odd local
        const int slot = (cl >> 3) ^ ((wp >> 1) & 3);
        const int boff = (isx1 ? X1_OFF : X0_OFF) + wp * 64 + slot * 16 + (cl & 7) * 2;
        const int ps = isx1 ? X1_PS : X0_PS;
        *(unsigned*)(smem + boff)      = pk0;          // parity 0
        *(unsigned*)(smem + boff + ps) = pk1;          // parity 1
      }
      __syncthreads();
      // ---- stats: per-position channel sum / sumsq, accumulate into y-windows ----
      for (int q0 = tid; q0 < 640; q0 += 512) {
        const bool sx1 = q0 >= 256;
        int par, pos, loc, base, stride; float *sa, *qa;
        if (!sx1) { par = q0 >> 7; pos = q0 & 127; base = X0_OFF + par * X0_PS;
                    loc = 2 * pos + par; sa = s0a; qa = sq0a; stride = 256; }
        else { const int q2 = q0 - 256; par = (q2 >= 192) ? 1 : 0; pos = q2 - par * 192;
               base = X1_OFF + par * X1_PS; loc = 2 * pos + par; sa = s1a; qa = sq1a; stride = 384; }
        float sm = 0.f, sq = 0.f;
#pragma unroll
        for (int sl = 0; sl < 4; ++sl) {
          const bf16x8_t v = *(const bf16x8_t*)(smem + base + pos * 64 + sl * 16);
#pragma unroll
          for (int e = 0; e < 8; ++e) {
            const float f = bf2f((unsigned short)v[e]);
            sm += f; sq += f * f;
          }
        }
#pragma unroll
        for (int t = 0; t < TY; ++t)
          if (t >= r - 2 && t <= r) { sa[t * stride + loc] += sm; qa[t * stride + loc] += sq; }
      }
      // ---- fragment loads + banded MFMA ----
      bf16x8_t afr[2], bfr[6];
#pragma unroll
      for (int mc = 0; mc < 2; ++mc) {
        const int pos = 16 * (chunk0 + mc) + lm;
        const int slot = lk ^ ((pos >> 1) & 3);
        afr[mc] = *(const bf16x8_t*)(smem + X0_OFF + p * X0_PS + pos * 64 + slot * 16);
      }
#pragma unroll
      for (int u = 0; u < 6; ++u) {
        const int pos = 16 * (chunk0 + u) + lm;
        const int slot = lk ^ ((pos >> 1) & 3);
        bfr[u] = *(const bf16x8_t*)(smem + X1_OFF + p * X1_PS + pos * 64 + slot * 16);
      }
#pragma unroll
      for (int t = 0; t < TY; ++t) {
        if (t >= r - 2 && t <= r) {
#pragma unroll
          for (int mc = 0; mc < 2; ++mc)
#pragma unroll
            for (int T = 0; T < 5; ++T)
              acc[t][mc][T] = __builtin_amdgcn_mfma_f32_16x16x32_bf16(
                  afr[mc], bfr[mc + T], acc[t][mc][T], 0, 0, 0);
        }
      }
    }
  }

  // ================= epilogue: per output row, x-box + normalize =================
  float* Q   = (float*)(smem + QB_OFF);
  float* s0x = (float*)(smem + S0X_OFF);
  float* l0x = (float*)(smem + L0X_OFF);
  float* s1x = (float*)(smem + S1X_OFF);
  float* l1x = (float*)(smem + L1X_OFF);
  const float invn = 1.f / 576.f;

  for (int t = 0; t < TY; ++t) {
    __syncthreads();
    // dump Q tiles: Q[di][x'_local], di = (d+64)/2 = n_glob - m_glob
#pragma unroll
    for (int mc = 0; mc < 2; ++mc) {
      const int m0 = 16 * (chunk0 + mc);
#pragma unroll
      for (int T = 0; T < 5; ++T) {
        const int n0 = 16 * (chunk0 + mc + T);
#pragma unroll
        for (int q = 0; q < 4; ++q) {
          const int mg = m0 + lk * 4 + q;
          const int ng = n0 + lm;
          const int di = ng - mg;
          if (di >= 0 && di <= 64)
            Q[di * 257 + 2 * mg + p] = acc[t][mc][T][q];
        }
      }
    }
    // boxed stats for this row
    for (int i = tid; i < 254; i += 512) {
      const float bs = s0a[t*256+i] + s0a[t*256+i+1] + s0a[t*256+i+2];
      const float bq = sq0a[t*256+i] + sq0a[t*256+i+1] + sq0a[t*256+i+2];
      s0x[i] = bs;
      l0x[i] = sqrtf(fmaxf(bq - bs * bs * invn, 0.f));
    }
    for (int i = tid; i < 382; i += 512) {
      const float bs = s1a[t*384+i] + s1a[t*384+i+1] + s1a[t*384+i+2];
      const float bq = sq1a[t*384+i] + sq1a[t*384+i+1] + sq1a[t*384+i+2];
      s1x[i] = bs;
      l1x[i] = sqrtf(fmaxf(bq - bs * bs * invn, 0.f));
    }
    __syncthreads();
    // outputs
    for (int oi = tid; oi < NDISP * TX; oi += 512) {
      const int di = oi / TX;
      const int xl = oi - di * TX;
      const int x = x0blk + xl;
      if (x < WIN) {
        const float q3 = Q[di*257+xl] + Q[di*257+xl+1] + Q[di*257+xl+2];
        const int vb = xl + 2 * di;                   // v_local base for s1/L1 box
        const float numer = q3 - s0x[xl] * s1x[vb] * invn;
        const float den = l0x[xl] * l1x[vb] + 1e-8f;
        out[(((size_t)b * NDISP + di) * HIN + (y0 + t)) * WIN + x] = numer / den;
      }
    }
  }
}

extern "C" void kernel_launch(void* const* d_in, const int* in_sizes, int n_in,
                              void* d_out, int out_size, void* d_ws, size_t ws_size,
                              hipStream_t stream) {
  const float* x0 = (const float*)d_in[0];
  const float* x1 = (const float*)d_in[1];
  float* out = (float*)d_out;
  dim3 grid(3, HIN / TY, BATCH);   // x-tiles {0,254,508}, 64 y-groups, 4 batches
  corrzn_kernel<<<grid, 512, 0, stream>>>(x0, x1, out);
}